// Round 1
// baseline (355.762 us; speedup 1.0000x reference)
//
#include <hip/hip_runtime.h>
#include <hip/hip_bf16.h>
#include <math.h>

// AttentionLayer: B=16, T=2048, D=256
// out[b,d,s] = h[b,s,d] + sum_t h[b,t,d] * softmax_s(m[b,t,:] @ aw[b,:,:]^T)[s]
//   h = in[...,0:256] + in[...,256:512]; m = tanh(h); aw = relu(h @ W^T + b)
// Pipeline: K0 prep -> Kw W-split -> K1 aw GEMM (split bf16) -> K2 lse pass -> K3 output pass.

#define NB 16
#define NT 2048
#define ND 256

typedef __attribute__((ext_vector_type(4))) float f32x4;
typedef __attribute__((ext_vector_type(8))) short s16x8;
typedef __attribute__((ext_vector_type(4))) short s16x4;

__device__ __forceinline__ unsigned short f2b(float x) {
  union { float f; unsigned u; } v; v.f = x;
  unsigned r = v.u + 0x7fffu + ((v.u >> 16) & 1u);  // RNE
  return (unsigned short)(r >> 16);
}
__device__ __forceinline__ float b2f(unsigned short h) {
  union { unsigned u; float f; } v; v.u = ((unsigned)h) << 16; return v.f;
}

// ---------------- K0: h = a+b halves; emit h_hi/h_lo/m (bf16, [B*T][D]) and hT (bf16, [B][D][T]) ----------------
__global__ __launch_bounds__(256) void k0_prep(const float* __restrict__ inF,
    unsigned short* __restrict__ h_hi, unsigned short* __restrict__ h_lo,
    unsigned short* __restrict__ m_b, unsigned short* __restrict__ hT)
{
  __shared__ __attribute__((aligned(16))) unsigned short ldsT[256][72];  // [d][t], padded row
  const int blk = blockIdx.x;
  const int b   = blk >> 5;           // /32
  const int t0  = (blk & 31) << 6;    // *64
  const int tid = threadIdx.x;
  const int tloc = tid >> 2;          // 0..63  (t row within tile)
  const int dseg = (tid & 3) << 6;    // 0/64/128/192
  const float* base = inF + ((size_t)(b * NT + t0 + tloc)) * (2 * ND);
  const size_t rowo = ((size_t)(b * NT + t0 + tloc)) * ND + dseg;
  #pragma unroll
  for (int j0 = 0; j0 < 64; j0 += 8) {
    const int dd = dseg + j0;
    float4 a0 = *(const float4*)(base + dd);
    float4 a1 = *(const float4*)(base + dd + 4);
    float4 c0 = *(const float4*)(base + ND + dd);
    float4 c1 = *(const float4*)(base + ND + dd + 4);
    float hv[8] = {a0.x + c0.x, a0.y + c0.y, a0.z + c0.z, a0.w + c0.w,
                   a1.x + c1.x, a1.y + c1.y, a1.z + c1.z, a1.w + c1.w};
    s16x8 vh, vl, vm;
    #pragma unroll
    for (int r = 0; r < 8; ++r) {
      unsigned short hh = f2b(hv[r]);
      vh[r] = (short)hh;
      vl[r] = (short)f2b(hv[r] - b2f(hh));
      vm[r] = (short)f2b(tanhf(hv[r]));
      ldsT[dd + r][tloc] = hh;
    }
    *(s16x8*)(h_hi + rowo + j0) = vh;
    *(s16x8*)(h_lo + rowo + j0) = vl;
    *(s16x8*)(m_b  + rowo + j0) = vm;
  }
  __syncthreads();
  #pragma unroll
  for (int rep = 0; rep < 8; ++rep) {
    const int d   = rep * 32 + (tid >> 3);
    const int seg = (tid & 7) * 8;
    s16x8 v = *(const s16x8*)&ldsT[d][seg];
    *(s16x8*)(hT + ((size_t)(b * ND + d)) * NT + t0 + seg) = v;
  }
}

// ---------------- Kw: W -> bf16 hi/lo split ----------------
__global__ __launch_bounds__(256) void kw_split(const float* __restrict__ W,
    unsigned short* __restrict__ W_hi, unsigned short* __restrict__ W_lo)
{
  const int idx = blockIdx.x * 256 + threadIdx.x;   // grid 256 -> 65536
  const float w = W[idx];
  const unsigned short hi = f2b(w);
  W_hi[idx] = hi;
  W_lo[idx] = f2b(w - b2f(hi));
}

// ---------------- K1: aw = relu(h @ W^T + b), split-bf16 (3 MFMA passes), bf16 out [B*T][D] ----------------
__global__ __launch_bounds__(256) void k1_aw(
    const unsigned short* __restrict__ h_hi, const unsigned short* __restrict__ h_lo,
    const unsigned short* __restrict__ W_hi, const unsigned short* __restrict__ W_lo,
    const float* __restrict__ bias, unsigned short* __restrict__ aw)
{
  const int row0 = blockIdx.x << 6;        // 512 blocks * 64 rows
  const int lane = threadIdx.x & 63;
  const int w    = threadIdx.x >> 6;       // wave 0..3 -> 16 rows each
  const int l15  = lane & 15;
  const int kg   = lane >> 4;
  f32x4 acc[16];
  #pragma unroll
  for (int i = 0; i < 16; ++i) acc[i] = (f32x4){0.f, 0.f, 0.f, 0.f};
  const size_t arow = (size_t)(row0 + w * 16 + l15) * ND + kg * 8;
  for (int ks = 0; ks < 8; ++ks) {
    s16x8 aH = *(const s16x8*)(h_hi + arow + ks * 32);
    s16x8 aL = *(const s16x8*)(h_lo + arow + ks * 32);
    #pragma unroll
    for (int et = 0; et < 16; ++et) {
      const size_t boff = (size_t)(et * 16 + l15) * ND + ks * 32 + kg * 8;
      s16x8 bH = *(const s16x8*)(W_hi + boff);
      s16x8 bL = *(const s16x8*)(W_lo + boff);
      acc[et] = __builtin_amdgcn_mfma_f32_16x16x32_bf16(aL, bH, acc[et], 0, 0, 0);
      acc[et] = __builtin_amdgcn_mfma_f32_16x16x32_bf16(aH, bL, acc[et], 0, 0, 0);
      acc[et] = __builtin_amdgcn_mfma_f32_16x16x32_bf16(aH, bH, acc[et], 0, 0, 0);
    }
  }
  #pragma unroll
  for (int et = 0; et < 16; ++et) {
    const int e = et * 16 + l15;
    const float bv = bias[e];
    #pragma unroll
    for (int r = 0; r < 4; ++r) {
      const int row = row0 + w * 16 + kg * 4 + r;
      float v = acc[et][r] + bv;
      aw[(size_t)row * ND + e] = f2b(v > 0.f ? v : 0.f);
    }
  }
}

// ---------------- K2: lse[b,t] = logsumexp_s( m[b,t,:] @ aw[b,s,:] ) ----------------
__global__ __launch_bounds__(256) void k2_lse(
    const unsigned short* __restrict__ m_b, const unsigned short* __restrict__ aw,
    float* __restrict__ lse)
{
  __shared__ __attribute__((aligned(16))) unsigned short awch[64][264];
  const int blk = blockIdx.x;
  const int b   = blk >> 5;
  const int t0  = (blk & 31) << 6;
  const int tid = threadIdx.x;
  const int lane = tid & 63;
  const int w    = tid >> 6;
  const int l15 = lane & 15, kg = lane >> 4;
  s16x8 afr[8];
  const size_t abase = ((size_t)(b * NT + t0 + w * 16 + l15)) * ND + kg * 8;
  #pragma unroll
  for (int ks = 0; ks < 8; ++ks) afr[ks] = *(const s16x8*)(m_b + abase + ks * 32);
  float mrow[4], lrow[4];
  #pragma unroll
  for (int r = 0; r < 4; ++r) { mrow[r] = -3e38f; lrow[r] = 0.f; }
  const unsigned short* awb = aw + (size_t)b * NT * ND;
  for (int ch = 0; ch < 32; ++ch) {
    const int s0 = ch << 6;
    __syncthreads();
    #pragma unroll
    for (int rep = 0; rep < 8; ++rep) {
      const int idx = rep * 2048 + tid * 8;
      const int srow = idx >> 8, col = idx & 255;
      *(s16x8*)&awch[srow][col] = *(const s16x8*)(awb + (size_t)(s0 + srow) * ND + col);
    }
    __syncthreads();
    f32x4 accS[4];
    #pragma unroll
    for (int st = 0; st < 4; ++st) accS[st] = (f32x4){0.f, 0.f, 0.f, 0.f};
    #pragma unroll
    for (int ks = 0; ks < 8; ++ks) {
      #pragma unroll
      for (int st = 0; st < 4; ++st) {
        s16x8 bf = *(const s16x8*)&awch[st * 16 + l15][ks * 32 + kg * 8];
        accS[st] = __builtin_amdgcn_mfma_f32_16x16x32_bf16(afr[ks], bf, accS[st], 0, 0, 0);
      }
    }
    #pragma unroll
    for (int r = 0; r < 4; ++r) {
      float v = fmaxf(fmaxf(accS[0][r], accS[1][r]), fmaxf(accS[2][r], accS[3][r]));
      #pragma unroll
      for (int o = 1; o < 16; o <<= 1) v = fmaxf(v, __shfl_xor(v, o, 64));
      const float nm = fmaxf(mrow[r], v);
      float ss = __expf(accS[0][r] - nm) + __expf(accS[1][r] - nm)
               + __expf(accS[2][r] - nm) + __expf(accS[3][r] - nm);
      #pragma unroll
      for (int o = 1; o < 16; o <<= 1) ss += __shfl_xor(ss, o, 64);
      lrow[r] = lrow[r] * __expf(mrow[r] - nm) + ss;
      mrow[r] = nm;
    }
  }
  if (l15 == 0) {
    #pragma unroll
    for (int r = 0; r < 4; ++r)
      lse[(size_t)b * NT + t0 + w * 16 + kg * 4 + r] = mrow[r] + __logf(lrow[r]);
  }
}

// ---------------- K3: O[s,d] = sum_t exp(S[t,s]-lse_t) h[t,d]; out[b,d,s] = h[b,s,d] + O[s,d] ----------------
__global__ __launch_bounds__(256) void k3_out(
    const unsigned short* __restrict__ m_b, const unsigned short* __restrict__ aw,
    const unsigned short* __restrict__ hT, const float* __restrict__ lse,
    float* __restrict__ outp)
{
  __shared__ __attribute__((aligned(16))) unsigned short awt[64][264];   // [s][k]
  __shared__ __attribute__((aligned(16))) unsigned short hTch[256][72];  // [d][t]
  __shared__ __attribute__((aligned(16))) unsigned short PT[64][72];     // [s][t]
  const int b  = blockIdx.y;
  const int s0 = blockIdx.x << 6;
  const int tid = threadIdx.x;
  const int lane = tid & 63;
  const int w    = tid >> 6;
  const int l15 = lane & 15, kg = lane >> 4;
  const unsigned short* awb = aw  + (size_t)b * NT * ND;
  const unsigned short* hTb = hT  + (size_t)b * ND * NT;
  const unsigned short* mbb = m_b + (size_t)b * NT * ND;
  #pragma unroll
  for (int rep = 0; rep < 8; ++rep) {
    const int idx = rep * 2048 + tid * 8;
    const int srow = idx >> 8, col = idx & 255;
    *(s16x8*)&awt[srow][col] = *(const s16x8*)(awb + (size_t)(s0 + srow) * ND + col);
  }
  f32x4 acc[16];
  #pragma unroll
  for (int i = 0; i < 16; ++i) acc[i] = (f32x4){0.f, 0.f, 0.f, 0.f};
  for (int ch = 0; ch < 32; ++ch) {
    const int t0 = ch << 6;
    __syncthreads();  // prev iter's GEMM2 done before restaging hTch/PT (covers awt on first iter)
    #pragma unroll
    for (int rep = 0; rep < 8; ++rep) {
      const int d   = rep * 32 + (tid >> 3);
      const int seg = (tid & 7) * 8;
      *(s16x8*)&hTch[d][seg] = *(const s16x8*)(hTb + (size_t)d * NT + t0 + seg);
    }
    s16x8 afr[8];
    const size_t abase = (size_t)(t0 + w * 16 + l15) * ND + kg * 8;
    #pragma unroll
    for (int ks = 0; ks < 8; ++ks) afr[ks] = *(const s16x8*)(mbb + abase + ks * 32);
    float c4[4];
    #pragma unroll
    for (int r = 0; r < 4; ++r) c4[r] = lse[(size_t)b * NT + t0 + w * 16 + kg * 4 + r];
    __syncthreads();
    // GEMM1: S_sub[t(16 per wave), s(64)] = m @ aw^T  (bitwise-identical to K2's)
    f32x4 accS[4];
    #pragma unroll
    for (int st = 0; st < 4; ++st) accS[st] = (f32x4){0.f, 0.f, 0.f, 0.f};
    #pragma unroll
    for (int ks = 0; ks < 8; ++ks) {
      #pragma unroll
      for (int st = 0; st < 4; ++st) {
        s16x8 bf = *(const s16x8*)&awt[st * 16 + l15][ks * 32 + kg * 8];
        accS[st] = __builtin_amdgcn_mfma_f32_16x16x32_bf16(afr[ks], bf, accS[st], 0, 0, 0);
      }
    }
    // P = exp(S - lse_t) -> PT[s][t] (transposed write, 4 consecutive t per lane)
    #pragma unroll
    for (int st = 0; st < 4; ++st) {
      s16x4 pv;
      #pragma unroll
      for (int r = 0; r < 4; ++r)
        pv[r] = (short)f2b(__expf(accS[st][r] - c4[r]));
      *(s16x4*)&PT[st * 16 + l15][w * 16 + kg * 4] = pv;
    }
    __syncthreads();
    // GEMM2: O[s(16 per wave), d(256)] += P^T @ h
    #pragma unroll
    for (int ks = 0; ks < 2; ++ks) {
      s16x8 af2 = *(const s16x8*)&PT[w * 16 + l15][ks * 32 + kg * 8];
      #pragma unroll
      for (int dt = 0; dt < 16; ++dt) {
        s16x8 bf2 = *(const s16x8*)&hTch[dt * 16 + l15][ks * 32 + kg * 8];
        acc[dt] = __builtin_amdgcn_mfma_f32_16x16x32_bf16(af2, bf2, acc[dt], 0, 0, 0);
      }
    }
  }
  // epilogue: out[b][d][s] = hT[d][s] + O[s][d]; 4 consecutive s per lane -> float4 store
  #pragma unroll
  for (int dt = 0; dt < 16; ++dt) {
    const int d = dt * 16 + l15;
    const size_t sbase = (size_t)s0 + w * 16 + kg * 4;
    s16x4 hres = *(const s16x4*)(hTb + (size_t)d * NT + sbase);
    float4 o;
    o.x = acc[dt][0] + b2f((unsigned short)hres[0]);
    o.y = acc[dt][1] + b2f((unsigned short)hres[1]);
    o.z = acc[dt][2] + b2f((unsigned short)hres[2]);
    o.w = acc[dt][3] + b2f((unsigned short)hres[3]);
    *(float4*)(outp + ((size_t)(b * ND + d)) * NT + sbase) = o;
  }
}

extern "C" void kernel_launch(void* const* d_in, const int* in_sizes, int n_in,
                              void* d_out, int out_size, void* d_ws, size_t ws_size,
                              hipStream_t stream) {
  const float* inF  = (const float*)d_in[0];  // [16][2048][512]
  const float* W    = (const float*)d_in[1];  // [256][256]
  const float* bias = (const float*)d_in[2];  // [256]
  float* outp = (float*)d_out;                // [16][256][2048]

  const size_t SZ = (size_t)NB * NT * ND;     // 8,388,608 elems
  unsigned short* h_hi = (unsigned short*)d_ws;
  unsigned short* h_lo = h_hi + SZ;
  unsigned short* m_b  = h_lo + SZ;
  unsigned short* hT   = m_b + SZ;
  unsigned short* awp  = hT + SZ;
  unsigned short* W_hi = awp + SZ;
  unsigned short* W_lo = W_hi + (size_t)ND * ND;
  float* lse = (float*)(W_lo + (size_t)ND * ND);
  const size_t need = (5 * SZ + 2 * (size_t)ND * ND) * sizeof(unsigned short)
                    + (size_t)NB * NT * sizeof(float);   // ~84.3 MB
  if (ws_size < need) return;  // visible failure (output stays poisoned) -> ws too small

  k0_prep<<<dim3(NB * NT / 64), dim3(256), 0, stream>>>(inF, h_hi, h_lo, m_b, hT);
  kw_split<<<dim3(ND * ND / 256), dim3(256), 0, stream>>>(W, W_hi, W_lo);
  k1_aw<<<dim3(NB * NT / 64), dim3(256), 0, stream>>>(h_hi, h_lo, W_hi, W_lo, bias, awp);
  k2_lse<<<dim3(NB * NT / 64), dim3(256), 0, stream>>>(m_b, awp, lse);
  k3_out<<<dim3(NT / 64, NB), dim3(256), 0, stream>>>(m_b, awp, hT, lse, outp);
}

// Round 2
// 301.212 us; speedup vs baseline: 1.1811x; 1.1811x over previous
//
#include <hip/hip_runtime.h>
#include <hip/hip_bf16.h>
#include <math.h>

// AttentionLayer: B=16, T=2048, D=256
// out[b,d,s] = h[b,s,d] + sum_t h[b,t,d] * softmax_s(m[b,t,:] @ aw[b,:,:]^T)[s]
//   h = in[...,0:256] + in[...,256:512]; m = tanh(h); aw = relu(h @ W^T + b)
// Kernels: kw_split (W->bf16 hi/lo) -> kprep (h,m,hT,aw fused) -> k2_z (lse, no max-tracking)
//          -> k3_out (recompute S, O = P^T @ h, residual). Single barrier per chunk in K2/K3.

#define NB 16
#define NT 2048
#define ND 256

typedef __attribute__((ext_vector_type(4))) float f32x4;
typedef __attribute__((ext_vector_type(8))) short s16x8;
typedef __attribute__((ext_vector_type(4))) short s16x4;
typedef unsigned short u16;

__device__ __forceinline__ u16 f2b(float x) {
  union { float f; unsigned u; } v; v.f = x;
  unsigned r = v.u + 0x7fffu + ((v.u >> 16) & 1u);  // RNE
  return (u16)(r >> 16);
}
__device__ __forceinline__ float b2f(u16 h) {
  union { unsigned u; float f; } v; v.u = ((unsigned)h) << 16; return v.f;
}

// ---------------- Kw: W -> bf16 hi/lo split ----------------
__global__ __launch_bounds__(256) void kw_split(const float* __restrict__ W,
    u16* __restrict__ W_hi, u16* __restrict__ W_lo)
{
  const int idx = blockIdx.x * 256 + threadIdx.x;   // grid 256 -> 65536
  const float w = W[idx];
  const u16 hi = f2b(w);
  W_hi[idx] = hi;
  W_lo[idx] = f2b(w - b2f(hi));
}

// ---------------- Kprep: h = a+b; emit m (bf16 [B*T][D]), hT (bf16 [B][D][T]), aw = relu(h@W^T+b) ----------------
__global__ __launch_bounds__(256, 2) void kprep(const float* __restrict__ inF,
    const u16* __restrict__ W_hi, const u16* __restrict__ W_lo, const float* __restrict__ bias,
    u16* __restrict__ m_b, u16* __restrict__ hT, u16* __restrict__ aw)
{
  __shared__ __attribute__((aligned(16))) u16 ldsT[256][72];  // [d][t] for hT transpose
  __shared__ __attribute__((aligned(16))) u16 hld[64][264];   // [t][d] bf16 h for GEMM A-frags
  const int blk = blockIdx.x;
  const int b   = blk >> 5;
  const int t0  = (blk & 31) << 6;
  const int tid = threadIdx.x;
  const int tloc = tid >> 2;          // 0..63
  const int dseg = (tid & 3) << 6;    // 0/64/128/192
  const float* base = inF + ((size_t)(b * NT + t0 + tloc)) * (2 * ND);
  const size_t rowo = ((size_t)(b * NT + t0 + tloc)) * ND + dseg;
  #pragma unroll
  for (int j0 = 0; j0 < 64; j0 += 8) {
    const int dd = dseg + j0;
    float4 a0 = *(const float4*)(base + dd);
    float4 a1 = *(const float4*)(base + dd + 4);
    float4 c0 = *(const float4*)(base + ND + dd);
    float4 c1 = *(const float4*)(base + ND + dd + 4);
    float hv[8] = {a0.x + c0.x, a0.y + c0.y, a0.z + c0.z, a0.w + c0.w,
                   a1.x + c1.x, a1.y + c1.y, a1.z + c1.z, a1.w + c1.w};
    s16x8 vh, vm;
    #pragma unroll
    for (int r = 0; r < 8; ++r) {
      u16 hh = f2b(hv[r]);
      vh[r] = (short)hh;
      vm[r] = (short)f2b(tanhf(hv[r]));
      ldsT[dd + r][tloc] = hh;
    }
    *(s16x8*)&hld[tloc][dd] = vh;
    *(s16x8*)(m_b + rowo + j0) = vm;
  }
  __syncthreads();
  // phase B: hT[b][d][t-chunk]
  #pragma unroll
  for (int rep = 0; rep < 8; ++rep) {
    const int d   = rep * 32 + (tid >> 3);
    const int seg = (tid & 7) * 8;
    *(s16x8*)(hT + ((size_t)(b * ND + d)) * NT + t0 + seg) = *(const s16x8*)&ldsT[d][seg];
  }
  // phase C: aw GEMM (W split hi/lo, h single bf16)
  const int lane = tid & 63;
  const int w    = tid >> 6;
  const int l15  = lane & 15, kg = lane >> 4;
  f32x4 acc[16];
  #pragma unroll
  for (int i = 0; i < 16; ++i) acc[i] = (f32x4){0.f, 0.f, 0.f, 0.f};
  for (int ks = 0; ks < 8; ++ks) {
    s16x8 aH = *(const s16x8*)&hld[w * 16 + l15][ks * 32 + kg * 8];
    #pragma unroll
    for (int et = 0; et < 16; ++et) {
      const size_t boff = (size_t)(et * 16 + l15) * ND + ks * 32 + kg * 8;
      s16x8 bH = *(const s16x8*)(W_hi + boff);
      s16x8 bL = *(const s16x8*)(W_lo + boff);
      acc[et] = __builtin_amdgcn_mfma_f32_16x16x32_bf16(aH, bL, acc[et], 0, 0, 0);
      acc[et] = __builtin_amdgcn_mfma_f32_16x16x32_bf16(aH, bH, acc[et], 0, 0, 0);
    }
  }
  #pragma unroll
  for (int et = 0; et < 16; ++et) {
    const int e = et * 16 + l15;
    const float bv = bias[e];
    #pragma unroll
    for (int r = 0; r < 4; ++r) {
      const size_t row = (size_t)(b * NT + t0 + w * 16 + kg * 4 + r);
      float v = acc[et][r] + bv;
      aw[row * ND + e] = f2b(v > 0.f ? v : 0.f);
    }
  }
}

// ---------------- K2: lse[b,t] = log( sum_s exp(m[b,t,:] @ aw[b,s,:]) )  (no max tracking) ----------------
__global__ __launch_bounds__(256, 2) void k2_z(
    const u16* __restrict__ m_b, const u16* __restrict__ aw, float* __restrict__ lse)
{
  __shared__ __attribute__((aligned(16))) u16 awch[2][64][264];
  const int blk = blockIdx.x;
  const int b   = blk >> 5;
  const int t0  = (blk & 31) << 6;
  const int tid = threadIdx.x;
  const int lane = tid & 63;
  const int w    = tid >> 6;
  const int l15 = lane & 15, kg = lane >> 4;
  s16x8 afr[8];
  const size_t abase = ((size_t)(b * NT + t0 + w * 16 + l15)) * ND + kg * 8;
  #pragma unroll
  for (int ks = 0; ks < 8; ++ks) afr[ks] = *(const s16x8*)(m_b + abase + ks * 32);
  const u16* awb = aw + (size_t)b * NT * ND;
  auto stage = [&](int ch, int buf) {
    const int s0 = ch << 6;
    #pragma unroll
    for (int rep = 0; rep < 8; ++rep) {
      const int idx = rep * 2048 + tid * 8;
      const int srow = idx >> 8, col = idx & 255;
      *(s16x8*)&awch[buf][srow][col] = *(const s16x8*)(awb + (size_t)(s0 + srow) * ND + col);
    }
  };
  stage(0, 0);
  float zacc[4] = {0.f, 0.f, 0.f, 0.f};
  __syncthreads();
  for (int ch = 0; ch < 32; ++ch) {
    const int c = ch & 1;
    if (ch < 31) stage(ch + 1, c ^ 1);
    f32x4 accS[4];
    #pragma unroll
    for (int st = 0; st < 4; ++st) accS[st] = (f32x4){0.f, 0.f, 0.f, 0.f};
    #pragma unroll
    for (int ks = 0; ks < 8; ++ks) {
      #pragma unroll
      for (int st = 0; st < 4; ++st) {
        s16x8 bf = *(const s16x8*)&awch[c][st * 16 + l15][ks * 32 + kg * 8];
        accS[st] = __builtin_amdgcn_mfma_f32_16x16x32_bf16(afr[ks], bf, accS[st], 0, 0, 0);
      }
    }
    #pragma unroll
    for (int st = 0; st < 4; ++st)
      #pragma unroll
      for (int r = 0; r < 4; ++r) zacc[r] += __expf(accS[st][r]);
    __syncthreads();
  }
  #pragma unroll
  for (int r = 0; r < 4; ++r) {
    #pragma unroll
    for (int o = 1; o < 16; o <<= 1) zacc[r] += __shfl_xor(zacc[r], o, 64);
  }
  if (l15 == 0) {
    #pragma unroll
    for (int r = 0; r < 4; ++r)
      lse[(size_t)b * NT + t0 + w * 16 + kg * 4 + r] = __logf(zacc[r]);
  }
}

// ---------------- K3: O[s,d] = sum_t exp(S[t,s]-lse_t) h[t,d]; out[b,d,s] = hT[d][s] + O[s,d] ----------------
// wave w owns d-slice [w*64, w*64+64), all 64 s of the block's s-tile.
__global__ __launch_bounds__(256, 3) void k3_out(
    const u16* __restrict__ m_b, const u16* __restrict__ aw,
    const u16* __restrict__ hT, const float* __restrict__ lse,
    float* __restrict__ outp)
{
  __shared__ __attribute__((aligned(16))) u16 awt[64][264];   // [s][k] staged once
  __shared__ __attribute__((aligned(16))) u16 PT[2][64][72];  // [s][t] double-buffered
  const int b  = blockIdx.y;
  const int s0 = blockIdx.x << 6;
  const int tid = threadIdx.x;
  const int lane = tid & 63;
  const int w    = tid >> 6;
  const int l15 = lane & 15, kg = lane >> 4;
  const u16* awb = aw  + (size_t)b * NT * ND;
  const u16* hTb = hT  + (size_t)b * ND * NT;
  const u16* mbb = m_b + (size_t)b * NT * ND;
  const float* lseb = lse + (size_t)b * NT;
  #pragma unroll
  for (int rep = 0; rep < 8; ++rep) {
    const int idx = rep * 2048 + tid * 8;
    const int srow = idx >> 8, col = idx & 255;
    *(s16x8*)&awt[srow][col] = *(const s16x8*)(awb + (size_t)(s0 + srow) * ND + col);
  }
  f32x4 acc[4][4];
  #pragma unroll
  for (int st = 0; st < 4; ++st)
    #pragma unroll
    for (int dt = 0; dt < 4; ++dt) acc[st][dt] = (f32x4){0.f, 0.f, 0.f, 0.f};

  auto g1 = [&](int ch, int buf) {   // S-tile for t-window [ch*64 + w*16, +16), P -> PT[buf]
    const int tb = ch << 6;
    s16x8 afr[8];
    const size_t ab = (size_t)(tb + w * 16 + l15) * ND + kg * 8;
    #pragma unroll
    for (int ks = 0; ks < 8; ++ks) afr[ks] = *(const s16x8*)(mbb + ab + ks * 32);
    f32x4 aS[4];
    #pragma unroll
    for (int st = 0; st < 4; ++st) aS[st] = (f32x4){0.f, 0.f, 0.f, 0.f};
    #pragma unroll
    for (int ks = 0; ks < 8; ++ks) {
      #pragma unroll
      for (int st = 0; st < 4; ++st) {
        s16x8 bf = *(const s16x8*)&awt[st * 16 + l15][ks * 32 + kg * 8];
        aS[st] = __builtin_amdgcn_mfma_f32_16x16x32_bf16(afr[ks], bf, aS[st], 0, 0, 0);
      }
    }
    float c4[4];
    #pragma unroll
    for (int r = 0; r < 4; ++r) c4[r] = lseb[tb + w * 16 + kg * 4 + r];
    #pragma unroll
    for (int st = 0; st < 4; ++st) {
      s16x4 pv;
      #pragma unroll
      for (int r = 0; r < 4; ++r) pv[r] = (short)f2b(__expf(aS[st][r] - c4[r]));
      *(s16x4*)&PT[buf][st * 16 + l15][w * 16 + kg * 4] = pv;
    }
  };
  auto g2 = [&](int ch, int buf) {   // acc[st][dt] += P^T @ h for this t-chunk
    const int tb = ch << 6;
    #pragma unroll
    for (int ks = 0; ks < 2; ++ks) {
      s16x8 pa[4];
      #pragma unroll
      for (int st = 0; st < 4; ++st)
        pa[st] = *(const s16x8*)&PT[buf][st * 16 + l15][ks * 32 + kg * 8];
      #pragma unroll
      for (int dt = 0; dt < 4; ++dt) {
        s16x8 hb = *(const s16x8*)(hTb + (size_t)(w * 64 + dt * 16 + l15) * NT + tb + ks * 32 + kg * 8);
        #pragma unroll
        for (int st = 0; st < 4; ++st)
          acc[st][dt] = __builtin_amdgcn_mfma_f32_16x16x32_bf16(pa[st], hb, acc[st][dt], 0, 0, 0);
      }
    }
  };

  __syncthreads();       // awt staged
  g1(0, 0);
  for (int ch = 0; ch < 32; ++ch) {
    __syncthreads();     // PT[ch&1] ready; all waves done reading PT[(ch-1)&1]
    if (ch < 31) g1(ch + 1, (ch + 1) & 1);
    g2(ch, ch & 1);
  }
  // epilogue: out[b][d][s] = hT[d][s] + O[s][d]
  #pragma unroll
  for (int st = 0; st < 4; ++st) {
    const int sb = s0 + st * 16 + kg * 4;
    #pragma unroll
    for (int dt = 0; dt < 4; ++dt) {
      const int d = w * 64 + dt * 16 + l15;
      s16x4 hres = *(const s16x4*)(hTb + (size_t)d * NT + sb);
      float4 o;
      o.x = acc[st][dt][0] + b2f((u16)hres[0]);
      o.y = acc[st][dt][1] + b2f((u16)hres[1]);
      o.z = acc[st][dt][2] + b2f((u16)hres[2]);
      o.w = acc[st][dt][3] + b2f((u16)hres[3]);
      *(float4*)(outp + ((size_t)(b * ND + d)) * NT + sb) = o;
    }
  }
}

extern "C" void kernel_launch(void* const* d_in, const int* in_sizes, int n_in,
                              void* d_out, int out_size, void* d_ws, size_t ws_size,
                              hipStream_t stream) {
  const float* inF  = (const float*)d_in[0];  // [16][2048][512]
  const float* W    = (const float*)d_in[1];  // [256][256]
  const float* bias = (const float*)d_in[2];  // [256]
  float* outp = (float*)d_out;                // [16][256][2048]

  const size_t SZ = (size_t)NB * NT * ND;     // 8,388,608 elems
  u16* m_b  = (u16*)d_ws;
  u16* hT   = m_b + SZ;
  u16* awp  = hT + SZ;
  u16* W_hi = awp + SZ;
  u16* W_lo = W_hi + (size_t)ND * ND;
  float* lse = (float*)(W_lo + (size_t)ND * ND);
  const size_t need = (3 * SZ + 2 * (size_t)ND * ND) * sizeof(u16)
                    + (size_t)NB * NT * sizeof(float);   // ~50.7 MB
  if (ws_size < need) return;  // visible failure (output stays poisoned)

  kw_split<<<dim3(ND * ND / 256), dim3(256), 0, stream>>>(W, W_hi, W_lo);
  kprep<<<dim3(NB * NT / 64), dim3(256), 0, stream>>>(inF, W_hi, W_lo, bias, m_b, hT, awp);
  k2_z<<<dim3(NB * NT / 64), dim3(256), 0, stream>>>(m_b, awp, lse);
  k3_out<<<dim3(NT / 64, NB), dim3(256), 0, stream>>>(m_b, awp, hT, lse, outp);
}

// Round 3
// 281.014 us; speedup vs baseline: 1.2660x; 1.0719x over previous
//
#include <hip/hip_runtime.h>
#include <hip/hip_bf16.h>
#include <math.h>

// AttentionLayer: B=16, T=2048, D=256
// out[b,d,s] = h[b,s,d] + sum_t h[b,t,d] * softmax_s(m[b,t,:] @ aw[b,:,:]^T)[s]
//   h = in[...,0:256] + in[...,256:512]; m = tanh(h); aw = relu(h @ W^T + b)
// Main path: kw_split -> kprep -> k2s (S GEMM, writes S^T fp16 + lse) -> k3o (exp + PV GEMM).
// Fallback path (small ws): r2 pipeline (k2_z + k3_out, S recomputed).

#define NB 16
#define NT 2048
#define ND 256

typedef __attribute__((ext_vector_type(4))) float f32x4;
typedef __attribute__((ext_vector_type(8))) short s16x8;
typedef __attribute__((ext_vector_type(4))) short s16x4;
typedef unsigned short u16;

__device__ __forceinline__ u16 f2b(float x) {
  union { float f; unsigned u; } v; v.f = x;
  unsigned r = v.u + 0x7fffu + ((v.u >> 16) & 1u);  // RNE
  return (u16)(r >> 16);
}
__device__ __forceinline__ float b2f(u16 h) {
  union { unsigned u; float f; } v; v.u = ((unsigned)h) << 16; return v.f;
}
__device__ __forceinline__ u16 f2h(float x) {
  union { _Float16 h; u16 u; } v; v.h = (_Float16)x; return v.u;
}
__device__ __forceinline__ float h2f(u16 u) {
  union { u16 u; _Float16 h; } v; v.u = u; return (float)v.h;
}
__device__ __forceinline__ float tanh_fast(float x) {
  // 1 - 2/(1+e^{2x}); exact at tails (e^inf -> 1, e^0 -> -1), branch-free
  return 1.f - 2.f / (1.f + __expf(2.f * x));
}

// ---------------- Kw: W -> bf16 hi/lo split ----------------
__global__ __launch_bounds__(256) void kw_split(const float* __restrict__ W,
    u16* __restrict__ W_hi, u16* __restrict__ W_lo)
{
  const int idx = blockIdx.x * 256 + threadIdx.x;
  const float w = W[idx];
  const u16 hi = f2b(w);
  W_hi[idx] = hi;
  W_lo[idx] = f2b(w - b2f(hi));
}

// ---------------- Kprep: h = a+b; emit m (bf16 [B*T][D]), hT (bf16 [B][D][T]), aw = relu(h@W^T+b) ----------------
__global__ __launch_bounds__(256, 2) void kprep(const float* __restrict__ inF,
    const u16* __restrict__ W_hi, const u16* __restrict__ W_lo, const float* __restrict__ bias,
    u16* __restrict__ m_b, u16* __restrict__ hT, u16* __restrict__ aw)
{
  __shared__ __attribute__((aligned(16))) u16 hld[64][264];   // [t][d] bf16 h
  const int blk = blockIdx.x;
  const int b   = blk >> 5;
  const int t0  = (blk & 31) << 6;
  const int tid = threadIdx.x;
  const int tloc = tid >> 2;          // 0..63
  const int dseg = (tid & 3) << 6;    // 0/64/128/192
  const float* base = inF + ((size_t)(b * NT + t0 + tloc)) * (2 * ND);
  const size_t rowo = ((size_t)(b * NT + t0 + tloc)) * ND + dseg;
  #pragma unroll
  for (int j0 = 0; j0 < 64; j0 += 8) {
    const int dd = dseg + j0;
    float4 a0 = *(const float4*)(base + dd);
    float4 a1 = *(const float4*)(base + dd + 4);
    float4 c0 = *(const float4*)(base + ND + dd);
    float4 c1 = *(const float4*)(base + ND + dd + 4);
    float hv[8] = {a0.x + c0.x, a0.y + c0.y, a0.z + c0.z, a0.w + c0.w,
                   a1.x + c1.x, a1.y + c1.y, a1.z + c1.z, a1.w + c1.w};
    s16x8 vh, vm;
    #pragma unroll
    for (int r = 0; r < 8; ++r) {
      vh[r] = (short)f2b(hv[r]);
      vm[r] = (short)f2b(tanh_fast(hv[r]));
    }
    *(s16x8*)&hld[tloc][dd] = vh;
    *(s16x8*)(m_b + rowo + j0) = vm;
  }
  __syncthreads();
  // phase B: hT[b][d][t-window] via read-side transpose of hld
  {
    const int d = tid;  // 0..255
    #pragma unroll
    for (int seg = 0; seg < 64; seg += 8) {
      s16x8 v;
      #pragma unroll
      for (int j = 0; j < 8; ++j) v[j] = (short)hld[seg + j][d];
      *(s16x8*)(hT + ((size_t)(b * ND + d)) * NT + t0 + seg) = v;
    }
  }
  // phase C: aw GEMM (W split hi/lo, h single bf16)
  const int lane = tid & 63;
  const int w    = tid >> 6;
  const int l15  = lane & 15, kg = lane >> 4;
  f32x4 acc[16];
  #pragma unroll
  for (int i = 0; i < 16; ++i) acc[i] = (f32x4){0.f, 0.f, 0.f, 0.f};
  for (int ks = 0; ks < 8; ++ks) {
    s16x8 aH = *(const s16x8*)&hld[w * 16 + l15][ks * 32 + kg * 8];
    #pragma unroll
    for (int et = 0; et < 16; ++et) {
      const size_t boff = (size_t)(et * 16 + l15) * ND + ks * 32 + kg * 8;
      s16x8 bH = *(const s16x8*)(W_hi + boff);
      s16x8 bL = *(const s16x8*)(W_lo + boff);
      acc[et] = __builtin_amdgcn_mfma_f32_16x16x32_bf16(aH, bL, acc[et], 0, 0, 0);
      acc[et] = __builtin_amdgcn_mfma_f32_16x16x32_bf16(aH, bH, acc[et], 0, 0, 0);
    }
  }
  #pragma unroll
  for (int et = 0; et < 16; ++et) {
    const int e = et * 16 + l15;
    const float bv = bias[e];
    #pragma unroll
    for (int r = 0; r < 4; ++r) {
      const size_t row = (size_t)(b * NT + t0 + w * 16 + kg * 4 + r);
      float v = acc[et][r] + bv;
      aw[row * ND + e] = f2b(v > 0.f ? v : 0.f);
    }
  }
}

// ---------------- K2s: S^T[b][s][t] (fp16) + lse[b,t] = log(sum_s exp(S)) ----------------
__global__ __launch_bounds__(256, 2) void k2s(
    const u16* __restrict__ m_b, const u16* __restrict__ aw,
    u16* __restrict__ STp, float* __restrict__ lse)
{
  __shared__ __attribute__((aligned(16))) u16 awch[2][64][264];
  const int blk = blockIdx.x;
  const int b   = blk >> 5;
  const int t0  = (blk & 31) << 6;
  const int tid = threadIdx.x;
  const int lane = tid & 63;
  const int w    = tid >> 6;
  const int l15 = lane & 15, kg = lane >> 4;
  s16x8 afr[8];
  const size_t abase = ((size_t)(b * NT + t0 + w * 16 + l15)) * ND + kg * 8;
  #pragma unroll
  for (int ks = 0; ks < 8; ++ks) afr[ks] = *(const s16x8*)(m_b + abase + ks * 32);
  const u16* awb = aw + (size_t)b * NT * ND;
  u16* STb = STp + (size_t)b * NT * NT;
  auto stage = [&](int ch, int buf) {
    const int s0 = ch << 6;
    #pragma unroll
    for (int rep = 0; rep < 8; ++rep) {
      const int idx = rep * 2048 + tid * 8;
      const int srow = idx >> 8, col = idx & 255;
      *(s16x8*)&awch[buf][srow][col] = *(const s16x8*)(awb + (size_t)(s0 + srow) * ND + col);
    }
  };
  stage(0, 0);
  float zacc[4] = {0.f, 0.f, 0.f, 0.f};
  __syncthreads();
  for (int ch = 0; ch < 32; ++ch) {
    const int c = ch & 1;
    const int s0c = ch << 6;
    if (ch < 31) stage(ch + 1, c ^ 1);
    f32x4 accS[4];
    #pragma unroll
    for (int st = 0; st < 4; ++st) accS[st] = (f32x4){0.f, 0.f, 0.f, 0.f};
    #pragma unroll
    for (int ks = 0; ks < 8; ++ks) {
      #pragma unroll
      for (int st = 0; st < 4; ++st) {
        s16x8 bf = *(const s16x8*)&awch[c][st * 16 + l15][ks * 32 + kg * 8];
        accS[st] = __builtin_amdgcn_mfma_f32_16x16x32_bf16(afr[ks], bf, accS[st], 0, 0, 0);
      }
    }
    // S^T write (fp16): lane's 4 values per st = consecutive t, fixed s
    #pragma unroll
    for (int st = 0; st < 4; ++st) {
      s16x4 sv;
      #pragma unroll
      for (int r = 0; r < 4; ++r) sv[r] = (short)f2h(accS[st][r]);
      *(s16x4*)(STb + (size_t)(s0c + st * 16 + l15) * NT + t0 + w * 16 + kg * 4) = sv;
      #pragma unroll
      for (int r = 0; r < 4; ++r) zacc[r] += __expf(accS[st][r]);
    }
    __syncthreads();
  }
  #pragma unroll
  for (int r = 0; r < 4; ++r) {
    #pragma unroll
    for (int o = 1; o < 16; o <<= 1) zacc[r] += __shfl_xor(zacc[r], o, 64);
  }
  if (l15 == 0) {
    #pragma unroll
    for (int r = 0; r < 4; ++r)
      lse[(size_t)b * NT + t0 + w * 16 + kg * 4 + r] = __logf(zacc[r]);
  }
}

// ---------------- K3o: O[s,d] = sum_t exp(S[t,s]-lse_t) h[t,d]; out[b,d,s] = hT[d][s] + O[s,d] ----------------
__global__ __launch_bounds__(256, 2) void k3o(
    const u16* __restrict__ STp, const u16* __restrict__ hT,
    const float* __restrict__ lse, float* __restrict__ outp)
{
  __shared__ __attribute__((aligned(16))) u16 PT[2][64][72];  // [s][t] bf16 P
  const int b  = blockIdx.y;
  const int s0 = blockIdx.x << 6;
  const int tid = threadIdx.x;
  const int lane = tid & 63;
  const int w    = tid >> 6;
  const int l15 = lane & 15, kg = lane >> 4;
  const u16* STb = STp + (size_t)b * NT * NT;
  const u16* hTb = hT  + (size_t)b * ND * NT;
  const float* lseb = lse + (size_t)b * NT;
  const int lrow = tid >> 2;          // 0..63 (s-row in tile)
  const int lseg = (tid & 3) << 4;    // 0/16/32/48 (t-offset)

  f32x4 acc[4][4];
  #pragma unroll
  for (int st = 0; st < 4; ++st)
    #pragma unroll
    for (int dt = 0; dt < 4; ++dt) acc[st][dt] = (f32x4){0.f, 0.f, 0.f, 0.f};

  // prologue: stage chunk 0 into PT[0]
  {
    s16x8 v0 = *(const s16x8*)(STb + (size_t)(s0 + lrow) * NT + lseg);
    s16x8 v1 = *(const s16x8*)(STb + (size_t)(s0 + lrow) * NT + lseg + 8);
    float4 La = *(const float4*)(lseb + lseg);
    float4 Lb = *(const float4*)(lseb + lseg + 4);
    float4 Lc = *(const float4*)(lseb + lseg + 8);
    float4 Ld = *(const float4*)(lseb + lseg + 12);
    float ls[16] = {La.x, La.y, La.z, La.w, Lb.x, Lb.y, Lb.z, Lb.w,
                    Lc.x, Lc.y, Lc.z, Lc.w, Ld.x, Ld.y, Ld.z, Ld.w};
    s16x8 p0, p1;
    #pragma unroll
    for (int j = 0; j < 8; ++j) p0[j] = (short)f2b(__expf(h2f((u16)v0[j]) - ls[j]));
    #pragma unroll
    for (int j = 0; j < 8; ++j) p1[j] = (short)f2b(__expf(h2f((u16)v1[j]) - ls[8 + j]));
    *(s16x8*)&PT[0][lrow][lseg] = p0;
    *(s16x8*)&PT[0][lrow][lseg + 8] = p1;
  }

  for (int ch = 0; ch < 32; ++ch) {
    const int cur = ch & 1;
    const int tb  = ch << 6;
    __syncthreads();   // PT[cur] ready; all waves done reading PT[cur^1]
    // issue next chunk's S/lse loads (land during MFMA below)
    s16x8 v0, v1;
    float ls[16];
    if (ch < 31) {
      const int tn = tb + 64;
      v0 = *(const s16x8*)(STb + (size_t)(s0 + lrow) * NT + tn + lseg);
      v1 = *(const s16x8*)(STb + (size_t)(s0 + lrow) * NT + tn + lseg + 8);
      float4 La = *(const float4*)(lseb + tn + lseg);
      float4 Lb = *(const float4*)(lseb + tn + lseg + 4);
      float4 Lc = *(const float4*)(lseb + tn + lseg + 8);
      float4 Ld = *(const float4*)(lseb + tn + lseg + 12);
      ls[0]=La.x; ls[1]=La.y; ls[2]=La.z; ls[3]=La.w;
      ls[4]=Lb.x; ls[5]=Lb.y; ls[6]=Lb.z; ls[7]=Lb.w;
      ls[8]=Lc.x; ls[9]=Lc.y; ls[10]=Lc.z; ls[11]=Lc.w;
      ls[12]=Ld.x; ls[13]=Ld.y; ls[14]=Ld.z; ls[15]=Ld.w;
    }
    // PV GEMM on PT[cur]: acc[st][dt] += P^T @ h
    #pragma unroll
    for (int ks = 0; ks < 2; ++ks) {
      s16x8 pa[4];
      #pragma unroll
      for (int st = 0; st < 4; ++st)
        pa[st] = *(const s16x8*)&PT[cur][st * 16 + l15][ks * 32 + kg * 8];
      #pragma unroll
      for (int dt = 0; dt < 4; ++dt) {
        s16x8 hb = *(const s16x8*)(hTb + (size_t)(w * 64 + dt * 16 + l15) * NT + tb + ks * 32 + kg * 8);
        #pragma unroll
        for (int st = 0; st < 4; ++st)
          acc[st][dt] = __builtin_amdgcn_mfma_f32_16x16x32_bf16(pa[st], hb, acc[st][dt], 0, 0, 0);
      }
    }
    // exp + write PT[cur^1] for next chunk
    if (ch < 31) {
      s16x8 p0, p1;
      #pragma unroll
      for (int j = 0; j < 8; ++j) p0[j] = (short)f2b(__expf(h2f((u16)v0[j]) - ls[j]));
      #pragma unroll
      for (int j = 0; j < 8; ++j) p1[j] = (short)f2b(__expf(h2f((u16)v1[j]) - ls[8 + j]));
      *(s16x8*)&PT[cur ^ 1][lrow][lseg] = p0;
      *(s16x8*)&PT[cur ^ 1][lrow][lseg + 8] = p1;
    }
  }
  // epilogue: out[b][d][s] = hT[d][s] + O[s][d]
  #pragma unroll
  for (int st = 0; st < 4; ++st) {
    const int sb = s0 + st * 16 + kg * 4;
    #pragma unroll
    for (int dt = 0; dt < 4; ++dt) {
      const int d = w * 64 + dt * 16 + l15;
      s16x4 hres = *(const s16x4*)(hTb + (size_t)d * NT + sb);
      float4 o;
      o.x = acc[st][dt][0] + b2f((u16)hres[0]);
      o.y = acc[st][dt][1] + b2f((u16)hres[1]);
      o.z = acc[st][dt][2] + b2f((u16)hres[2]);
      o.w = acc[st][dt][3] + b2f((u16)hres[3]);
      *(float4*)(outp + ((size_t)(b * ND + d)) * NT + sb) = o;
    }
  }
}

// ================= Fallback path (small workspace): r2 pipeline =================
__global__ __launch_bounds__(256, 2) void k2_z(
    const u16* __restrict__ m_b, const u16* __restrict__ aw, float* __restrict__ lse)
{
  __shared__ __attribute__((aligned(16))) u16 awch[2][64][264];
  const int blk = blockIdx.x;
  const int b   = blk >> 5;
  const int t0  = (blk & 31) << 6;
  const int tid = threadIdx.x;
  const int lane = tid & 63;
  const int w    = tid >> 6;
  const int l15 = lane & 15, kg = lane >> 4;
  s16x8 afr[8];
  const size_t abase = ((size_t)(b * NT + t0 + w * 16 + l15)) * ND + kg * 8;
  #pragma unroll
  for (int ks = 0; ks < 8; ++ks) afr[ks] = *(const s16x8*)(m_b + abase + ks * 32);
  const u16* awb = aw + (size_t)b * NT * ND;
  auto stage = [&](int ch, int buf) {
    const int s0 = ch << 6;
    #pragma unroll
    for (int rep = 0; rep < 8; ++rep) {
      const int idx = rep * 2048 + tid * 8;
      const int srow = idx >> 8, col = idx & 255;
      *(s16x8*)&awch[buf][srow][col] = *(const s16x8*)(awb + (size_t)(s0 + srow) * ND + col);
    }
  };
  stage(0, 0);
  float zacc[4] = {0.f, 0.f, 0.f, 0.f};
  __syncthreads();
  for (int ch = 0; ch < 32; ++ch) {
    const int c = ch & 1;
    if (ch < 31) stage(ch + 1, c ^ 1);
    f32x4 accS[4];
    #pragma unroll
    for (int st = 0; st < 4; ++st) accS[st] = (f32x4){0.f, 0.f, 0.f, 0.f};
    #pragma unroll
    for (int ks = 0; ks < 8; ++ks) {
      #pragma unroll
      for (int st = 0; st < 4; ++st) {
        s16x8 bf = *(const s16x8*)&awch[c][st * 16 + l15][ks * 32 + kg * 8];
        accS[st] = __builtin_amdgcn_mfma_f32_16x16x32_bf16(afr[ks], bf, accS[st], 0, 0, 0);
      }
    }
    #pragma unroll
    for (int st = 0; st < 4; ++st)
      #pragma unroll
      for (int r = 0; r < 4; ++r) zacc[r] += __expf(accS[st][r]);
    __syncthreads();
  }
  #pragma unroll
  for (int r = 0; r < 4; ++r) {
    #pragma unroll
    for (int o = 1; o < 16; o <<= 1) zacc[r] += __shfl_xor(zacc[r], o, 64);
  }
  if (l15 == 0) {
    #pragma unroll
    for (int r = 0; r < 4; ++r)
      lse[(size_t)b * NT + t0 + w * 16 + kg * 4 + r] = __logf(zacc[r]);
  }
}

__global__ __launch_bounds__(256, 3) void k3_out(
    const u16* __restrict__ m_b, const u16* __restrict__ aw,
    const u16* __restrict__ hT, const float* __restrict__ lse,
    float* __restrict__ outp)
{
  __shared__ __attribute__((aligned(16))) u16 awt[64][264];
  __shared__ __attribute__((aligned(16))) u16 PT[2][64][72];
  const int b  = blockIdx.y;
  const int s0 = blockIdx.x << 6;
  const int tid = threadIdx.x;
  const int lane = tid & 63;
  const int w    = tid >> 6;
  const int l15 = lane & 15, kg = lane >> 4;
  const u16* awb = aw  + (size_t)b * NT * ND;
  const u16* hTb = hT  + (size_t)b * ND * NT;
  const u16* mbb = m_b + (size_t)b * NT * ND;
  const float* lseb = lse + (size_t)b * NT;
  #pragma unroll
  for (int rep = 0; rep < 8; ++rep) {
    const int idx = rep * 2048 + tid * 8;
    const int srow = idx >> 8, col = idx & 255;
    *(s16x8*)&awt[srow][col] = *(const s16x8*)(awb + (size_t)(s0 + srow) * ND + col);
  }
  f32x4 acc[4][4];
  #pragma unroll
  for (int st = 0; st < 4; ++st)
    #pragma unroll
    for (int dt = 0; dt < 4; ++dt) acc[st][dt] = (f32x4){0.f, 0.f, 0.f, 0.f};

  auto g1 = [&](int ch, int buf) {
    const int tb = ch << 6;
    s16x8 afr[8];
    const size_t ab = (size_t)(tb + w * 16 + l15) * ND + kg * 8;
    #pragma unroll
    for (int ks = 0; ks < 8; ++ks) afr[ks] = *(const s16x8*)(mbb + ab + ks * 32);
    f32x4 aS[4];
    #pragma unroll
    for (int st = 0; st < 4; ++st) aS[st] = (f32x4){0.f, 0.f, 0.f, 0.f};
    #pragma unroll
    for (int ks = 0; ks < 8; ++ks) {
      #pragma unroll
      for (int st = 0; st < 4; ++st) {
        s16x8 bf = *(const s16x8*)&awt[st * 16 + l15][ks * 32 + kg * 8];
        aS[st] = __builtin_amdgcn_mfma_f32_16x16x32_bf16(afr[ks], bf, aS[st], 0, 0, 0);
      }
    }
    float c4[4];
    #pragma unroll
    for (int r = 0; r < 4; ++r) c4[r] = lseb[tb + w * 16 + kg * 4 + r];
    #pragma unroll
    for (int st = 0; st < 4; ++st) {
      s16x4 pv;
      #pragma unroll
      for (int r = 0; r < 4; ++r) pv[r] = (short)f2b(__expf(aS[st][r] - c4[r]));
      *(s16x4*)&PT[buf][st * 16 + l15][w * 16 + kg * 4] = pv;
    }
  };
  auto g2 = [&](int ch, int buf) {
    const int tb = ch << 6;
    #pragma unroll
    for (int ks = 0; ks < 2; ++ks) {
      s16x8 pa[4];
      #pragma unroll
      for (int st = 0; st < 4; ++st)
        pa[st] = *(const s16x8*)&PT[buf][st * 16 + l15][ks * 32 + kg * 8];
      #pragma unroll
      for (int dt = 0; dt < 4; ++dt) {
        s16x8 hb = *(const s16x8*)(hTb + (size_t)(w * 64 + dt * 16 + l15) * NT + tb + ks * 32 + kg * 8);
        #pragma unroll
        for (int st = 0; st < 4; ++st)
          acc[st][dt] = __builtin_amdgcn_mfma_f32_16x16x32_bf16(pa[st], hb, acc[st][dt], 0, 0, 0);
      }
    }
  };

  __syncthreads();
  g1(0, 0);
  for (int ch = 0; ch < 32; ++ch) {
    __syncthreads();
    if (ch < 31) g1(ch + 1, (ch + 1) & 1);
    g2(ch, ch & 1);
  }
  #pragma unroll
  for (int st = 0; st < 4; ++st) {
    const int sb = s0 + st * 16 + kg * 4;
    #pragma unroll
    for (int dt = 0; dt < 4; ++dt) {
      const int d = w * 64 + dt * 16 + l15;
      s16x4 hres = *(const s16x4*)(hTb + (size_t)d * NT + sb);
      float4 o;
      o.x = acc[st][dt][0] + b2f((u16)hres[0]);
      o.y = acc[st][dt][1] + b2f((u16)hres[1]);
      o.z = acc[st][dt][2] + b2f((u16)hres[2]);
      o.w = acc[st][dt][3] + b2f((u16)hres[3]);
      *(float4*)(outp + ((size_t)(b * ND + d)) * NT + sb) = o;
    }
  }
}

extern "C" void kernel_launch(void* const* d_in, const int* in_sizes, int n_in,
                              void* d_out, int out_size, void* d_ws, size_t ws_size,
                              hipStream_t stream) {
  const float* inF  = (const float*)d_in[0];  // [16][2048][512]
  const float* W    = (const float*)d_in[1];  // [256][256]
  const float* bias = (const float*)d_in[2];  // [256]
  float* outp = (float*)d_out;                // [16][256][2048]

  const size_t SZ = (size_t)NB * NT * ND;     // 8,388,608 elems
  u16* m_b  = (u16*)d_ws;
  u16* hT   = m_b + SZ;
  u16* awp  = hT + SZ;
  u16* W_hi = awp + SZ;
  u16* W_lo = W_hi + (size_t)ND * ND;
  float* lse = (float*)(W_lo + (size_t)ND * ND);
  u16* STp  = (u16*)(lse + (size_t)NB * NT);  // fp16 S^T [B][s][t], 128 MiB
  const size_t need_small = (3 * SZ + 2 * (size_t)ND * ND) * sizeof(u16)
                          + (size_t)NB * NT * sizeof(float);
  const size_t need_big = need_small + (size_t)NB * NT * NT * sizeof(u16);
  if (ws_size < need_small) return;  // visible failure

  kw_split<<<dim3(ND * ND / 256), dim3(256), 0, stream>>>(W, W_hi, W_lo);
  kprep<<<dim3(NB * NT / 64), dim3(256), 0, stream>>>(inF, W_hi, W_lo, bias, m_b, hT, awp);
  if (ws_size >= need_big) {
    k2s<<<dim3(NB * NT / 64), dim3(256), 0, stream>>>(m_b, awp, STp, lse);
    k3o<<<dim3(NT / 64, NB), dim3(256), 0, stream>>>(STp, hT, lse, outp);
  } else {
    k2_z<<<dim3(NB * NT / 64), dim3(256), 0, stream>>>(m_b, awp, lse);
    k3_out<<<dim3(NT / 64, NB), dim3(256), 0, stream>>>(m_b, awp, hT, lse, outp);
  }
}

// Round 4
// 250.458 us; speedup vs baseline: 1.4204x; 1.1220x over previous
//
#include <hip/hip_runtime.h>
#include <hip/hip_bf16.h>
#include <math.h>

// AttentionLayer: B=16, T=2048, D=256
// out[b,d,s] = h[b,s,d] + sum_t h[b,t,d] * softmax_s(m[b,t,:] @ aw[b,:,:]^T)[s]
//   h = in[...,0:256] + in[...,256:512]; m = tanh(h); aw = relu(h @ W^T + b)
// Pipeline (all intermediates fp16):
//   kA: streaming prep -> h16 [B*T][D], m16 [B*T][D], hT16 [B][D][T]
//   kB: aw GEMM, W staged fp32->fp16 in LDS once per block, no inner barriers
//   k2s: S = m @ aw^T -> S^T fp16 [B][s][t] + lse
//   k3o: P = exp(S-lse) -> PV GEMM + residual
// h16 aliases the first 16MB of the S^T region (dead after kB, overwritten by k2s).

#define NB 16
#define NT 2048
#define ND 256

typedef __attribute__((ext_vector_type(4))) float f32x4;
typedef __attribute__((ext_vector_type(8))) short s16x8;
typedef __attribute__((ext_vector_type(4))) short s16x4;
typedef __attribute__((ext_vector_type(8))) _Float16 f16x8;
typedef unsigned short u16;

__device__ __forceinline__ u16 f2h(float x) {
  union { _Float16 h; u16 u; } v; v.h = (_Float16)x; return v.u;
}
__device__ __forceinline__ float h2f(u16 u) {
  union { u16 u; _Float16 h; } v; v.u = u; return (float)v.h;
}
__device__ __forceinline__ float tanh_fast(float x) {
  return 1.f - 2.f / (1.f + __expf(2.f * x));  // exact at tails, branch-free
}

// ---------------- kA: h = a+b; h16 [t][d], m16 [t][d], hT16 [d][t] ----------------
__global__ __launch_bounds__(256, 4) void kA(const float* __restrict__ inF,
    u16* __restrict__ h16, u16* __restrict__ m16, u16* __restrict__ hT16)
{
  __shared__ __attribute__((aligned(16))) u16 hld[64][264];   // [t][d] fp16 h
  const int blk = blockIdx.x;
  const int b   = blk >> 5;
  const int t0  = (blk & 31) << 6;
  const int tid = threadIdx.x;
  const int tloc = tid >> 2;          // 0..63
  const int dseg = (tid & 3) << 6;    // 0/64/128/192
  const float* base = inF + ((size_t)(b * NT + t0 + tloc)) * (2 * ND);
  const size_t rowo = ((size_t)(b * NT + t0 + tloc)) * ND + dseg;
  #pragma unroll
  for (int j0 = 0; j0 < 64; j0 += 8) {
    const int dd = dseg + j0;
    float4 a0 = *(const float4*)(base + dd);
    float4 a1 = *(const float4*)(base + dd + 4);
    float4 c0 = *(const float4*)(base + ND + dd);
    float4 c1 = *(const float4*)(base + ND + dd + 4);
    float hv[8] = {a0.x + c0.x, a0.y + c0.y, a0.z + c0.z, a0.w + c0.w,
                   a1.x + c1.x, a1.y + c1.y, a1.z + c1.z, a1.w + c1.w};
    s16x8 vh, vm;
    #pragma unroll
    for (int r = 0; r < 8; ++r) {
      vh[r] = (short)f2h(hv[r]);
      vm[r] = (short)f2h(tanh_fast(hv[r]));
    }
    *(s16x8*)&hld[tloc][dd] = vh;
    *(s16x8*)(h16 + rowo + j0) = vh;
    *(s16x8*)(m16 + rowo + j0) = vm;
  }
  __syncthreads();
  // read-side transpose: hT16[b][d][t0..t0+64)
  {
    const int d = tid;  // 0..255
    #pragma unroll
    for (int seg = 0; seg < 64; seg += 8) {
      s16x8 v;
      #pragma unroll
      for (int j = 0; j < 8; ++j) v[j] = (short)hld[seg + j][d];
      *(s16x8*)(hT16 + ((size_t)(b * ND + d)) * NT + t0 + seg) = v;
    }
  }
}

// ---------------- kB: aw = relu(h @ W^T + b), fp16, W half staged in LDS ----------------
// block = 128 rows x 128 e; grid (256 row-tiles, 2 e-halves)
__global__ __launch_bounds__(256, 2) void kB(const u16* __restrict__ h16,
    const float* __restrict__ W, const float* __restrict__ bias, u16* __restrict__ aw16)
{
  __shared__ __attribute__((aligned(16))) u16 Wl[128][264];   // fp16 W[e0+.., k]
  const int r0 = blockIdx.x << 7;
  const int e0 = blockIdx.y << 7;
  const int tid = threadIdx.x;
  // stage W (fp32 -> fp16): 128x256 elems, 128 per thread
  #pragma unroll
  for (int rep = 0; rep < 16; ++rep) {
    const int idx = rep * 2048 + tid * 8;
    const int er = idx >> 8, col = idx & 255;
    float4 x0 = *(const float4*)(W + (size_t)(e0 + er) * ND + col);
    float4 x1 = *(const float4*)(W + (size_t)(e0 + er) * ND + col + 4);
    s16x8 v;
    v[0] = (short)f2h(x0.x); v[1] = (short)f2h(x0.y); v[2] = (short)f2h(x0.z); v[3] = (short)f2h(x0.w);
    v[4] = (short)f2h(x1.x); v[5] = (short)f2h(x1.y); v[6] = (short)f2h(x1.z); v[7] = (short)f2h(x1.w);
    *(s16x8*)&Wl[er][col] = v;
  }
  const int lane = tid & 63;
  const int w    = tid >> 6;
  const int l15  = lane & 15, kg = lane >> 4;
  float bv[8];
  #pragma unroll
  for (int et = 0; et < 8; ++et) bv[et] = bias[e0 + et * 16 + l15];
  f32x4 acc[2][8];
  #pragma unroll
  for (int rt = 0; rt < 2; ++rt)
    #pragma unroll
    for (int et = 0; et < 8; ++et) acc[rt][et] = (f32x4){0.f, 0.f, 0.f, 0.f};
  __syncthreads();
  #pragma unroll
  for (int ks = 0; ks < 8; ++ks) {
    f16x8 af[2];
    #pragma unroll
    for (int rt = 0; rt < 2; ++rt)
      af[rt] = *(const f16x8*)(h16 + (size_t)(r0 + w * 32 + rt * 16 + l15) * ND + ks * 32 + kg * 8);
    #pragma unroll
    for (int et = 0; et < 8; ++et) {
      f16x8 bf = *(const f16x8*)&Wl[et * 16 + l15][ks * 32 + kg * 8];
      #pragma unroll
      for (int rt = 0; rt < 2; ++rt)
        acc[rt][et] = __builtin_amdgcn_mfma_f32_16x16x32_f16(af[rt], bf, acc[rt][et], 0, 0, 0);
    }
  }
  #pragma unroll
  for (int rt = 0; rt < 2; ++rt)
    #pragma unroll
    for (int et = 0; et < 8; ++et) {
      const int e = e0 + et * 16 + l15;
      #pragma unroll
      for (int r = 0; r < 4; ++r) {
        const int row = r0 + w * 32 + rt * 16 + kg * 4 + r;
        float v = acc[rt][et][r] + bv[et];
        aw16[(size_t)row * ND + e] = f2h(v > 0.f ? v : 0.f);
      }
    }
}

// ---------------- k2s: S^T[b][s][t] (fp16) + lse[b,t] = log(sum_s exp(S)) ----------------
__global__ __launch_bounds__(256, 2) void k2s(
    const u16* __restrict__ m16, const u16* __restrict__ aw16,
    u16* __restrict__ STp, float* __restrict__ lse)
{
  __shared__ __attribute__((aligned(16))) u16 awch[2][64][264];
  const int blk = blockIdx.x;
  const int b   = blk >> 5;
  const int t0  = (blk & 31) << 6;
  const int tid = threadIdx.x;
  const int lane = tid & 63;
  const int w    = tid >> 6;
  const int l15 = lane & 15, kg = lane >> 4;
  f16x8 afr[8];
  const size_t abase = ((size_t)(b * NT + t0 + w * 16 + l15)) * ND + kg * 8;
  #pragma unroll
  for (int ks = 0; ks < 8; ++ks) afr[ks] = *(const f16x8*)(m16 + abase + ks * 32);
  const u16* awb = aw16 + (size_t)b * NT * ND;
  u16* STb = STp + (size_t)b * NT * NT;
  auto stage = [&](int ch, int buf) {
    const int s0 = ch << 6;
    #pragma unroll
    for (int rep = 0; rep < 8; ++rep) {
      const int idx = rep * 2048 + tid * 8;
      const int srow = idx >> 8, col = idx & 255;
      *(s16x8*)&awch[buf][srow][col] = *(const s16x8*)(awb + (size_t)(s0 + srow) * ND + col);
    }
  };
  stage(0, 0);
  float zacc[4] = {0.f, 0.f, 0.f, 0.f};
  __syncthreads();
  for (int ch = 0; ch < 32; ++ch) {
    const int c = ch & 1;
    const int s0c = ch << 6;
    if (ch < 31) stage(ch + 1, c ^ 1);
    f32x4 accS[4];
    #pragma unroll
    for (int st = 0; st < 4; ++st) accS[st] = (f32x4){0.f, 0.f, 0.f, 0.f};
    #pragma unroll
    for (int ks = 0; ks < 8; ++ks) {
      #pragma unroll
      for (int st = 0; st < 4; ++st) {
        f16x8 bf = *(const f16x8*)&awch[c][st * 16 + l15][ks * 32 + kg * 8];
        accS[st] = __builtin_amdgcn_mfma_f32_16x16x32_f16(afr[ks], bf, accS[st], 0, 0, 0);
      }
    }
    // S^T write (fp16) + Z accumulate
    #pragma unroll
    for (int st = 0; st < 4; ++st) {
      s16x4 sv;
      #pragma unroll
      for (int r = 0; r < 4; ++r) sv[r] = (short)f2h(accS[st][r]);
      *(s16x4*)(STb + (size_t)(s0c + st * 16 + l15) * NT + t0 + w * 16 + kg * 4) = sv;
      #pragma unroll
      for (int r = 0; r < 4; ++r) zacc[r] += __expf(accS[st][r]);
    }
    __syncthreads();
  }
  #pragma unroll
  for (int r = 0; r < 4; ++r) {
    #pragma unroll
    for (int o = 1; o < 16; o <<= 1) zacc[r] += __shfl_xor(zacc[r], o, 64);
  }
  if (l15 == 0) {
    #pragma unroll
    for (int r = 0; r < 4; ++r)
      lse[(size_t)b * NT + t0 + w * 16 + kg * 4 + r] = __logf(zacc[r]);
  }
}

// ---------------- k3o: O[s,d] = sum_t exp(S[t,s]-lse_t) h[t,d]; out = hT + O^T ----------------
__global__ __launch_bounds__(256, 2) void k3o(
    const u16* __restrict__ STp, const u16* __restrict__ hT16,
    const float* __restrict__ lse, float* __restrict__ outp)
{
  __shared__ __attribute__((aligned(16))) u16 PT[2][64][72];  // [s][t] fp16 P
  const int b  = blockIdx.y;
  const int s0 = blockIdx.x << 6;
  const int tid = threadIdx.x;
  const int lane = tid & 63;
  const int w    = tid >> 6;
  const int l15 = lane & 15, kg = lane >> 4;
  const u16* STb = STp + (size_t)b * NT * NT;
  const u16* hTb = hT16 + (size_t)b * ND * NT;
  const float* lseb = lse + (size_t)b * NT;
  const int lrow = tid >> 2;          // 0..63 (s-row in tile)
  const int lseg = (tid & 3) << 4;    // 0/16/32/48 (t-offset)

  f32x4 acc[4][4];
  #pragma unroll
  for (int st = 0; st < 4; ++st)
    #pragma unroll
    for (int dt = 0; dt < 4; ++dt) acc[st][dt] = (f32x4){0.f, 0.f, 0.f, 0.f};

  // prologue: stage chunk 0 into PT[0]
  {
    s16x8 v0 = *(const s16x8*)(STb + (size_t)(s0 + lrow) * NT + lseg);
    s16x8 v1 = *(const s16x8*)(STb + (size_t)(s0 + lrow) * NT + lseg + 8);
    float ls[16];
    #pragma unroll
    for (int j = 0; j < 16; j += 4) {
      float4 L = *(const float4*)(lseb + lseg + j);
      ls[j] = L.x; ls[j+1] = L.y; ls[j+2] = L.z; ls[j+3] = L.w;
    }
    s16x8 p0, p1;
    #pragma unroll
    for (int j = 0; j < 8; ++j) p0[j] = (short)f2h(__expf(h2f((u16)v0[j]) - ls[j]));
    #pragma unroll
    for (int j = 0; j < 8; ++j) p1[j] = (short)f2h(__expf(h2f((u16)v1[j]) - ls[8 + j]));
    *(s16x8*)&PT[0][lrow][lseg] = p0;
    *(s16x8*)&PT[0][lrow][lseg + 8] = p1;
  }

  for (int ch = 0; ch < 32; ++ch) {
    const int cur = ch & 1;
    const int tb  = ch << 6;
    __syncthreads();   // PT[cur] ready; all waves done reading PT[cur^1]
    s16x8 v0, v1;
    float ls[16];
    if (ch < 31) {
      const int tn = tb + 64;
      v0 = *(const s16x8*)(STb + (size_t)(s0 + lrow) * NT + tn + lseg);
      v1 = *(const s16x8*)(STb + (size_t)(s0 + lrow) * NT + tn + lseg + 8);
      #pragma unroll
      for (int j = 0; j < 16; j += 4) {
        float4 L = *(const float4*)(lseb + tn + lseg + j);
        ls[j] = L.x; ls[j+1] = L.y; ls[j+2] = L.z; ls[j+3] = L.w;
      }
    }
    // PV GEMM on PT[cur]
    #pragma unroll
    for (int ks = 0; ks < 2; ++ks) {
      f16x8 pa[4];
      #pragma unroll
      for (int st = 0; st < 4; ++st)
        pa[st] = *(const f16x8*)&PT[cur][st * 16 + l15][ks * 32 + kg * 8];
      #pragma unroll
      for (int dt = 0; dt < 4; ++dt) {
        f16x8 hb = *(const f16x8*)(hTb + (size_t)(w * 64 + dt * 16 + l15) * NT + tb + ks * 32 + kg * 8);
        #pragma unroll
        for (int st = 0; st < 4; ++st)
          acc[st][dt] = __builtin_amdgcn_mfma_f32_16x16x32_f16(pa[st], hb, acc[st][dt], 0, 0, 0);
      }
    }
    // exp + write PT[cur^1] for next chunk
    if (ch < 31) {
      s16x8 p0, p1;
      #pragma unroll
      for (int j = 0; j < 8; ++j) p0[j] = (short)f2h(__expf(h2f((u16)v0[j]) - ls[j]));
      #pragma unroll
      for (int j = 0; j < 8; ++j) p1[j] = (short)f2h(__expf(h2f((u16)v1[j]) - ls[8 + j]));
      *(s16x8*)&PT[cur ^ 1][lrow][lseg] = p0;
      *(s16x8*)&PT[cur ^ 1][lrow][lseg + 8] = p1;
    }
  }
  // epilogue: out[b][d][s] = hT[d][s] + O[s][d]
  #pragma unroll
  for (int st = 0; st < 4; ++st) {
    const int sb = s0 + st * 16 + kg * 4;
    #pragma unroll
    for (int dt = 0; dt < 4; ++dt) {
      const int d = w * 64 + dt * 16 + l15;
      const u16* hres = hTb + (size_t)d * NT + sb;
      float4 o;
      o.x = acc[st][dt][0] + h2f(hres[0]);
      o.y = acc[st][dt][1] + h2f(hres[1]);
      o.z = acc[st][dt][2] + h2f(hres[2]);
      o.w = acc[st][dt][3] + h2f(hres[3]);
      *(float4*)(outp + ((size_t)(b * ND + d)) * NT + sb) = o;
    }
  }
}

extern "C" void kernel_launch(void* const* d_in, const int* in_sizes, int n_in,
                              void* d_out, int out_size, void* d_ws, size_t ws_size,
                              hipStream_t stream) {
  const float* inF  = (const float*)d_in[0];  // [16][2048][512]
  const float* W    = (const float*)d_in[1];  // [256][256]
  const float* bias = (const float*)d_in[2];  // [256]
  float* outp = (float*)d_out;                // [16][256][2048]

  const size_t SZ = (size_t)NB * NT * ND;     // 8,388,608 elems
  u16* m16  = (u16*)d_ws;
  u16* hT16 = m16 + SZ;
  u16* aw16 = hT16 + SZ;
  float* lse = (float*)(aw16 + SZ);
  u16* STp  = (u16*)(lse + (size_t)NB * NT);  // fp16 S^T [B][s][t], 128 MiB
  u16* h16  = STp;                             // alias: dead after kB, overwritten by k2s
  const size_t need = 3 * SZ * sizeof(u16) + (size_t)NB * NT * sizeof(float)
                    + (size_t)NB * NT * NT * sizeof(u16);   // ~176.2 MB (< r3's proven 178.8)
  if (ws_size < need) return;  // visible failure (output stays poisoned)

  kA <<<dim3(NB * NT / 64), dim3(256), 0, stream>>>(inF, h16, m16, hT16);
  kB <<<dim3(256, 2), dim3(256), 0, stream>>>(h16, W, bias, aw16);
  k2s<<<dim3(NB * NT / 64), dim3(256), 0, stream>>>(m16, aw16, STp, lse);
  k3o<<<dim3(NT / 64, NB), dim3(256), 0, stream>>>(STp, hT16, lse, outp);
}

// Round 5
// 227.169 us; speedup vs baseline: 1.5661x; 1.1025x over previous
//
#include <hip/hip_runtime.h>
#include <hip/hip_bf16.h>
#include <math.h>

// AttentionLayer: B=16, T=2048, D=256
// out[b,d,s] = h[b,s,d] + sum_t h[b,t,d] * softmax_s(m[b,t,:] @ aw[b,:,:]^T)[s]
//   h = in[...,0:256] + in[...,256:512]; m = tanh(h); aw = relu(h @ W^T + b)
// Pipeline (fp16 intermediates):
//   kA: prep -> h16 [t][d], m16 [t][d], hfrag (MFMA-B-fragment tiled h^T)
//   kB: aw GEMM (W staged fp32->fp16 in LDS)
//   k2s: S = m @ aw^T -> Sfrag (MFMA-A-fragment tiled S^T, coalesced stores) + lse
//   k3o: barrier-free, LDS-free: load S-frag -> exp -> MFMA PV, residual epilogue
// Frag layouts:
//   Sfrag[b][s/16][t/32][lane][8]: value(s,t) at lane=(s&15)+16*((t&31)>>3), j=t&7
//   hfrag[b][d/16][t/32][lane][8]: value(d,t) same mapping with d in place of s
// h16 aliases the first 16MB of the Sfrag region (dead after kB, overwritten by k2s).

#define NB 16
#define NT 2048
#define ND 256

typedef __attribute__((ext_vector_type(4))) float f32x4;
typedef __attribute__((ext_vector_type(8))) short s16x8;
typedef __attribute__((ext_vector_type(4))) short s16x4;
typedef __attribute__((ext_vector_type(8))) _Float16 f16x8;
typedef unsigned short u16;

__device__ __forceinline__ u16 f2h(float x) {
  union { _Float16 h; u16 u; } v; v.h = (_Float16)x; return v.u;
}
__device__ __forceinline__ float h2f(u16 u) {
  union { u16 u; _Float16 h; } v; v.u = u; return (float)v.h;
}
__device__ __forceinline__ float tanh_fast(float x) {
  return 1.f - 2.f / (1.f + __expf(2.f * x));  // exact at tails, branch-free
}

// ---------------- kA: h = a+b; h16 [t][d], m16 [t][d], hfrag [d/16][t/32][lane][8] ----------------
__global__ __launch_bounds__(256, 4) void kA(const float* __restrict__ inF,
    u16* __restrict__ h16, u16* __restrict__ m16, u16* __restrict__ hfrag)
{
  __shared__ __attribute__((aligned(16))) u16 hld[64][264];   // [t][d] fp16 h
  const int blk = blockIdx.x;
  const int b   = blk >> 5;
  const int t0  = (blk & 31) << 6;
  const int tid = threadIdx.x;
  const int tloc = tid >> 2;          // 0..63
  const int dseg = (tid & 3) << 6;    // 0/64/128/192
  const float* base = inF + ((size_t)(b * NT + t0 + tloc)) * (2 * ND);
  const size_t rowo = ((size_t)(b * NT + t0 + tloc)) * ND + dseg;
  #pragma unroll
  for (int j0 = 0; j0 < 64; j0 += 8) {
    const int dd = dseg + j0;
    float4 a0 = *(const float4*)(base + dd);
    float4 a1 = *(const float4*)(base + dd + 4);
    float4 c0 = *(const float4*)(base + ND + dd);
    float4 c1 = *(const float4*)(base + ND + dd + 4);
    float hv[8] = {a0.x + c0.x, a0.y + c0.y, a0.z + c0.z, a0.w + c0.w,
                   a1.x + c1.x, a1.y + c1.y, a1.z + c1.z, a1.w + c1.w};
    s16x8 vh, vm;
    #pragma unroll
    for (int r = 0; r < 8; ++r) {
      vh[r] = (short)f2h(hv[r]);
      vm[r] = (short)f2h(tanh_fast(hv[r]));
    }
    *(s16x8*)&hld[tloc][dd] = vh;
    *(s16x8*)(h16 + rowo + j0) = vh;
    *(s16x8*)(m16 + rowo + j0) = vm;
  }
  __syncthreads();
  // phase B: hfrag slots. 2048 slots of 16B; thread handles 8 consecutive.
  u16* Hb = hfrag + (size_t)b * ND * NT;
  const int slot0 = tid * 8;
  #pragma unroll
  for (int rep = 0; rep < 8; ++rep) {
    const int slot = slot0 + rep;
    const int fi = slot >> 6;          // 0..31 (dtile*2 + ttile)
    const int lp = slot & 63;
    const int dtile = fi >> 1, ttile = fi & 1;
    const int d  = dtile * 16 + (lp & 15);
    const int tb = ttile * 32 + (lp >> 4) * 8;
    s16x8 v;
    #pragma unroll
    for (int j = 0; j < 8; ++j) v[j] = (short)hld[tb + j][d];
    *(s16x8*)(Hb + (((size_t)dtile * (NT / 32) + (t0 >> 5) + ttile) * 64 + lp) * 8) = v;
  }
}

// ---------------- kB: aw = relu(h @ W^T + b), fp16, W half staged in LDS ----------------
__global__ __launch_bounds__(256, 2) void kB(const u16* __restrict__ h16,
    const float* __restrict__ W, const float* __restrict__ bias, u16* __restrict__ aw16)
{
  __shared__ __attribute__((aligned(16))) u16 Wl[128][264];
  const int r0 = blockIdx.x << 7;
  const int e0 = blockIdx.y << 7;
  const int tid = threadIdx.x;
  #pragma unroll
  for (int rep = 0; rep < 16; ++rep) {
    const int idx = rep * 2048 + tid * 8;
    const int er = idx >> 8, col = idx & 255;
    float4 x0 = *(const float4*)(W + (size_t)(e0 + er) * ND + col);
    float4 x1 = *(const float4*)(W + (size_t)(e0 + er) * ND + col + 4);
    s16x8 v;
    v[0] = (short)f2h(x0.x); v[1] = (short)f2h(x0.y); v[2] = (short)f2h(x0.z); v[3] = (short)f2h(x0.w);
    v[4] = (short)f2h(x1.x); v[5] = (short)f2h(x1.y); v[6] = (short)f2h(x1.z); v[7] = (short)f2h(x1.w);
    *(s16x8*)&Wl[er][col] = v;
  }
  const int lane = tid & 63;
  const int w    = tid >> 6;
  const int l15  = lane & 15, kg = lane >> 4;
  float bv[8];
  #pragma unroll
  for (int et = 0; et < 8; ++et) bv[et] = bias[e0 + et * 16 + l15];
  f32x4 acc[2][8];
  #pragma unroll
  for (int rt = 0; rt < 2; ++rt)
    #pragma unroll
    for (int et = 0; et < 8; ++et) acc[rt][et] = (f32x4){0.f, 0.f, 0.f, 0.f};
  __syncthreads();
  #pragma unroll
  for (int ks = 0; ks < 8; ++ks) {
    f16x8 af[2];
    #pragma unroll
    for (int rt = 0; rt < 2; ++rt)
      af[rt] = *(const f16x8*)(h16 + (size_t)(r0 + w * 32 + rt * 16 + l15) * ND + ks * 32 + kg * 8);
    #pragma unroll
    for (int et = 0; et < 8; ++et) {
      f16x8 bf = *(const f16x8*)&Wl[et * 16 + l15][ks * 32 + kg * 8];
      #pragma unroll
      for (int rt = 0; rt < 2; ++rt)
        acc[rt][et] = __builtin_amdgcn_mfma_f32_16x16x32_f16(af[rt], bf, acc[rt][et], 0, 0, 0);
    }
  }
  #pragma unroll
  for (int rt = 0; rt < 2; ++rt)
    #pragma unroll
    for (int et = 0; et < 8; ++et) {
      const int e = e0 + et * 16 + l15;
      #pragma unroll
      for (int r = 0; r < 4; ++r) {
        const int row = r0 + w * 32 + rt * 16 + kg * 4 + r;
        float v = acc[rt][et][r] + bv[et];
        aw16[(size_t)row * ND + e] = f2h(v > 0.f ? v : 0.f);
      }
    }
}

// ---------------- k2s: Sfrag (fp16, fragment-tiled) + lse[b,t] = log(sum_s exp(S)) ----------------
__global__ __launch_bounds__(256, 2) void k2s(
    const u16* __restrict__ m16, const u16* __restrict__ aw16,
    u16* __restrict__ Sfrag, float* __restrict__ lse)
{
  __shared__ __attribute__((aligned(16))) u16 awch[2][64][264];
  const int blk = blockIdx.x;
  const int b   = blk >> 5;
  const int t0  = (blk & 31) << 6;
  const int tid = threadIdx.x;
  const int lane = tid & 63;
  const int w    = tid >> 6;
  const int l15 = lane & 15, kg = lane >> 4;
  f16x8 afr[8];
  const size_t abase = ((size_t)(b * NT + t0 + w * 16 + l15)) * ND + kg * 8;
  #pragma unroll
  for (int ks = 0; ks < 8; ++ks) afr[ks] = *(const f16x8*)(m16 + abase + ks * 32);
  const u16* awb = aw16 + (size_t)b * NT * ND;
  u16* STb = Sfrag + (size_t)b * NT * NT;
  // frag-store constants for this thread
  const int ti    = (t0 >> 5) + (w >> 1);
  const int lanep = l15 + 16 * ((w & 1) * 2 + (kg >> 1));
  const int jp    = (kg & 1) * 4;
  auto stage = [&](int ch, int buf) {
    const int s0 = ch << 6;
    #pragma unroll
    for (int rep = 0; rep < 8; ++rep) {
      const int idx = rep * 2048 + tid * 8;
      const int srow = idx >> 8, col = idx & 255;
      *(s16x8*)&awch[buf][srow][col] = *(const s16x8*)(awb + (size_t)(s0 + srow) * ND + col);
    }
  };
  stage(0, 0);
  float zacc[4] = {0.f, 0.f, 0.f, 0.f};
  __syncthreads();
  for (int ch = 0; ch < 32; ++ch) {
    const int c = ch & 1;
    if (ch < 31) stage(ch + 1, c ^ 1);
    f32x4 accS[4];
    #pragma unroll
    for (int st = 0; st < 4; ++st) accS[st] = (f32x4){0.f, 0.f, 0.f, 0.f};
    #pragma unroll
    for (int ks = 0; ks < 8; ++ks) {
      #pragma unroll
      for (int st = 0; st < 4; ++st) {
        f16x8 bf = *(const f16x8*)&awch[c][st * 16 + l15][ks * 32 + kg * 8];
        accS[st] = __builtin_amdgcn_mfma_f32_16x16x32_f16(afr[ks], bf, accS[st], 0, 0, 0);
      }
    }
    // frag-layout S store (coalesced 512B per wave-st) + Z accumulate
    #pragma unroll
    for (int st = 0; st < 4; ++st) {
      const int si = ch * 4 + st;
      s16x4 sv;
      #pragma unroll
      for (int r = 0; r < 4; ++r) sv[r] = (short)f2h(accS[st][r]);
      *(s16x4*)(STb + (((size_t)si * 64 + ti) * 64 + lanep) * 8 + jp) = sv;
      #pragma unroll
      for (int r = 0; r < 4; ++r) zacc[r] += __expf(accS[st][r]);
    }
    __syncthreads();
  }
  #pragma unroll
  for (int r = 0; r < 4; ++r) {
    #pragma unroll
    for (int o = 1; o < 16; o <<= 1) zacc[r] += __shfl_xor(zacc[r], o, 64);
  }
  if (l15 == 0) {
    #pragma unroll
    for (int r = 0; r < 4; ++r)
      lse[(size_t)b * NT + t0 + w * 16 + kg * 4 + r] = __logf(zacc[r]);
  }
}

// ---------------- k3o: barrier-free PV. O[s,d] = sum_t exp(S-lse) h; out = h^T + O^T ----------------
__global__ __launch_bounds__(256, 2) void k3o(
    const u16* __restrict__ Sfrag, const u16* __restrict__ hfrag,
    const float* __restrict__ lse, float* __restrict__ outp)
{
  const int b   = blockIdx.y;
  const int s0t = blockIdx.x;          // s-tile of 64 (0..31)
  const int tid = threadIdx.x;
  const int lane = tid & 63;
  const int w    = tid >> 6;           // wave owns d-slice [w*64, +64)
  const int l15 = lane & 15, kg = lane >> 4;
  const u16* Sb = Sfrag + (size_t)b * NT * NT;
  const u16* Hb = hfrag + (size_t)b * ND * NT;
  const float* lseb = lse + (size_t)b * NT;

  f32x4 acc[4][4];
  #pragma unroll
  for (int st = 0; st < 4; ++st)
    #pragma unroll
    for (int dt = 0; dt < 4; ++dt) acc[st][dt] = (f32x4){0.f, 0.f, 0.f, 0.f};

  const u16* sp[4];
  #pragma unroll
  for (int st = 0; st < 4; ++st)
    sp[st] = Sb + (((size_t)(s0t * 4 + st) * 64) * 64 + lane) * 8;
  const u16* hp[4];
  #pragma unroll
  for (int dt = 0; dt < 4; ++dt)
    hp[dt] = Hb + (((size_t)(w * 4 + dt) * 64) * 64 + lane) * 8;

  s16x8 sA[4][2], sB[4][2];

  auto loadS = [&](s16x8 (&dst)[4][2], int ch) {
    #pragma unroll
    for (int st = 0; st < 4; ++st)
      #pragma unroll
      for (int ks = 0; ks < 2; ++ks)
        dst[st][ks] = *(const s16x8*)(sp[st] + (size_t)(ch * 2 + ks) * 512);
  };

  auto compute = [&](s16x8 (&S)[4][2], int ch) {
    f16x8 hb[4][2];
    #pragma unroll
    for (int dt = 0; dt < 4; ++dt)
      #pragma unroll
      for (int ks = 0; ks < 2; ++ks)
        hb[dt][ks] = *(const f16x8*)(hp[dt] + (size_t)(ch * 2 + ks) * 512);
    #pragma unroll
    for (int ks = 0; ks < 2; ++ks) {
      const int tb = ch * 64 + ks * 32 + kg * 8;
      float4 La  = *(const float4*)(lseb + tb);
      float4 Lb4 = *(const float4*)(lseb + tb + 4);
      const float nl[8] = {La.x, La.y, La.z, La.w, Lb4.x, Lb4.y, Lb4.z, Lb4.w};
      f16x8 pa[4];
      #pragma unroll
      for (int st = 0; st < 4; ++st)
        #pragma unroll
        for (int j = 0; j < 8; ++j)
          pa[st][j] = (_Float16)__expf(h2f((u16)S[st][ks][j]) - nl[j]);
      #pragma unroll
      for (int dt = 0; dt < 4; ++dt)
        #pragma unroll
        for (int st = 0; st < 4; ++st)
          acc[st][dt] = __builtin_amdgcn_mfma_f32_16x16x32_f16(pa[st], hb[dt][ks], acc[st][dt], 0, 0, 0);
    }
  };

  loadS(sA, 0);
  for (int ch = 0; ch < 32; ch += 2) {
    loadS(sB, ch + 1);
    compute(sA, ch);
    if (ch + 2 < 32) loadS(sA, ch + 2);
    compute(sB, ch + 1);
  }
  // epilogue: out[b][d][s] = h[d][s] + O[s][d]; residual h from hfrag
  #pragma unroll
  for (int st = 0; st < 4; ++st) {
    const int sb = s0t * 64 + st * 16 + kg * 4;
    #pragma unroll
    for (int dt = 0; dt < 4; ++dt) {
      const int d = w * 64 + dt * 16 + l15;
      const u16* hres = Hb + (((size_t)(w * 4 + dt) * 64 + (s0t * 2 + (st >> 1))) * 64
                        + (l15 + 16 * ((st & 1) * 2 + (kg >> 1)))) * 8 + (kg & 1) * 4;
      float4 o;
      o.x = acc[st][dt][0] + h2f(hres[0]);
      o.y = acc[st][dt][1] + h2f(hres[1]);
      o.z = acc[st][dt][2] + h2f(hres[2]);
      o.w = acc[st][dt][3] + h2f(hres[3]);
      *(float4*)(outp + ((size_t)(b * ND + d)) * NT + sb) = o;
    }
  }
}

extern "C" void kernel_launch(void* const* d_in, const int* in_sizes, int n_in,
                              void* d_out, int out_size, void* d_ws, size_t ws_size,
                              hipStream_t stream) {
  const float* inF  = (const float*)d_in[0];  // [16][2048][512]
  const float* W    = (const float*)d_in[1];  // [256][256]
  const float* bias = (const float*)d_in[2];  // [256]
  float* outp = (float*)d_out;                // [16][256][2048]

  const size_t SZ = (size_t)NB * NT * ND;     // 8,388,608 elems
  u16* m16   = (u16*)d_ws;
  u16* hfrag = m16 + SZ;
  u16* aw16  = hfrag + SZ;
  float* lse = (float*)(aw16 + SZ);
  u16* Sfrag = (u16*)(lse + (size_t)NB * NT); // fp16 fragment-tiled S^T, 128 MiB
  u16* h16   = Sfrag;                          // alias: dead after kB, overwritten by k2s
  const size_t need = 3 * SZ * sizeof(u16) + (size_t)NB * NT * sizeof(float)
                    + (size_t)NB * NT * NT * sizeof(u16);   // ~176.2 MB (proven present in r3/r4)
  if (ws_size < need) return;  // visible failure (output stays poisoned)

  kA <<<dim3(NB * NT / 64), dim3(256), 0, stream>>>(inF, h16, m16, hfrag);
  kB <<<dim3(256, 2), dim3(256), 0, stream>>>(h16, W, bias, aw16);
  k2s<<<dim3(NB * NT / 64), dim3(256), 0, stream>>>(m16, aw16, Sfrag, lse);
  k3o<<<dim3(NT / 64, NB), dim3(256), 0, stream>>>(Sfrag, hfrag, lse, outp);
}